// Round 5
// baseline (136.145 us; speedup 1.0000x reference)
//
#include <hip/hip_runtime.h>
#include <math.h>

#define GAMMA 0.25f
constexpr int B_ = 8, Q_ = 64, N_ = 8192, K_ = 512, C_ = 256;

typedef __attribute__((ext_vector_type(8))) short bf16x8;
typedef __attribute__((ext_vector_type(4))) short short4v;
typedef __attribute__((ext_vector_type(4))) float f32x4;

static __device__ inline short f2bf(float x) {   // RNE float->bf16 bits
    union { float f; unsigned u; } v; v.f = x;
    unsigned r = (v.u + 0x7fffu + ((v.u >> 16) & 1u)) >> 16;
    return (short)r;
}
static __device__ inline float bf2f(short h) {
    union { unsigned u; float f; } v; v.u = ((unsigned)(unsigned short)h) << 16;
    return v.f;
}

// ---------------------------------------------------------------------------
// prep: emb fp32[512][64] -> bf16 embB[512][64] + e2[k]=||bf16(emb_k)||^2 in ws.
// ---------------------------------------------------------------------------
__global__ __launch_bounds__(256) void prep_kernel(const float* __restrict__ emb,
                                                   short* __restrict__ embB,
                                                   float* __restrict__ e2g)
{
    const int r = blockIdx.x * 256 + threadIdx.x;
    if (r >= K_) return;
    const float4* src = (const float4*)(emb + r * Q_);
    short4v* dst = (short4v*)(embB + r * Q_);
    float s = 0.f;
    #pragma unroll
    for (int i = 0; i < 16; ++i) {
        const float4 v = src[i];
        short4v h;
        h[0] = f2bf(v.x); h[1] = f2bf(v.y); h[2] = f2bf(v.z); h[3] = f2bf(v.w);
        dst[i] = h;
        #pragma unroll
        for (int j = 0; j < 4; ++j) { const float a = bf2f(h[j]); s = fmaf(a, a, s); }
    }
    e2g[r] = s;
}

// ---------------------------------------------------------------------------
// CE v2: DRAM-row-contiguous streaming.
// 256 blocks x 512 threads (8 waves); block owns 256 items (1 KB per class
// row -> every wave-load instr = 64 lanes x float4 = 1 KB CONTIGUOUS, one
// DRAM row region). Wave w sums exp over classes [32w, 32w+32) for ALL 256
// items; lane l owns items [4l,4l+4). Per-item totals combine via an 8-way
// LDS reduce (no cross-lane shuffles in the hot path).
// Old layout (32-item blocks) read 128-B chunks strided 32 KB -> every HBM
// access opened a new DRAM row (~1.5-2 TB/s effective, R3 counter evidence).
// ---------------------------------------------------------------------------
__global__ void ce_kernel(const float* __restrict__ qp,
                          const int* __restrict__ tgt,
                          float* __restrict__ cePart)
{
    __shared__ f32x4 parts[8][64];           // [wave][lane] = 8 KB
    const int tid  = threadIdx.x;
    const int lane = tid & 63;
    const int w    = tid >> 6;

    const int base = blockIdx.x * 256;       // 256-aligned => b uniform
    const int b    = base >> 13;
    const int n0   = base & (N_ - 1);
    const float* qpb = qp + (size_t)b * C_ * N_;
    const float* qpn = qpb + n0 + lane * 4;  // lane's 4 items within the row

    // target gather (wave 0 only) — issued first, consumed after barrier
    float xts[4] = {0.f, 0.f, 0.f, 0.f};
    if (w == 0) {
        #pragma unroll
        for (int j = 0; j < 4; ++j) {
            const int t = tgt[base + lane * 4 + j];
            xts[j] = qpb[(size_t)t * N_ + n0 + lane * 4 + j];
        }
    }

    // 32 classes x 1 KB contiguous; two 16-load halves so ~16 stay in flight
    f32x4 acc = {0.f, 0.f, 0.f, 0.f};
    const int cw = w * 32;
    float4 v0[16], v1[16];
    #pragma unroll
    for (int j = 0; j < 16; ++j)
        v0[j] = *(const float4*)(qpn + (size_t)(cw + j) * N_);
    #pragma unroll
    for (int j = 0; j < 16; ++j)
        v1[j] = *(const float4*)(qpn + (size_t)(cw + 16 + j) * N_);
    #pragma unroll
    for (int j = 0; j < 16; ++j) {
        acc[0] += __expf(v0[j].x); acc[1] += __expf(v0[j].y);
        acc[2] += __expf(v0[j].z); acc[3] += __expf(v0[j].w);
    }
    #pragma unroll
    for (int j = 0; j < 16; ++j) {
        acc[0] += __expf(v1[j].x); acc[1] += __expf(v1[j].y);
        acc[2] += __expf(v1[j].z); acc[3] += __expf(v1[j].w);
    }

    parts[w][lane] = acc;
    __syncthreads();

    if (w == 0) {
        f32x4 tot = ((parts[0][lane] + parts[1][lane]) +
                     (parts[2][lane] + parts[3][lane])) +
                    ((parts[4][lane] + parts[5][lane]) +
                     (parts[6][lane] + parts[7][lane]));
        float loss = 0.f;
        #pragma unroll
        for (int j = 0; j < 4; ++j) loss += __logf(tot[j]) - xts[j];
        #pragma unroll
        for (int off = 32; off > 0; off >>= 1) loss += __shfl_down(loss, off, 64);
        if (lane == 0) cePart[blockIdx.x] = loss;
    }
}

// ---------------------------------------------------------------------------
// VQ: verified round-4 kernel, verbatim (attribution: any dur delta is CE's).
// ---------------------------------------------------------------------------
__global__ __launch_bounds__(256) void vq_kernel(const float* __restrict__ ze,
                                                 const short* __restrict__ embB,
                                                 const float* __restrict__ e2g,
                                                 float* __restrict__ vqPart)
{
    __shared__ float smem[256];              // per-item min buffer
    const int tid  = threadIdx.x;
    const int lane = tid & 63;
    const int w    = tid >> 6;
    const int n16  = lane & 15;
    const int quad = lane >> 4;

    const int base = blockIdx.x * 64;        // 64-aligned => b uniform
    const int b    = base >> 13;
    const int n0   = base & (N_ - 1);
    const float* zb = ze + (size_t)b * Q_ * N_;

    // ---- A loads; convert to bf16(-2z) + exact fp32 zsq as they land ----
    bf16x8 afrag[4][2];
    float zsq = 0.f;
    #pragma unroll
    for (int u = 0; u < 4; ++u) {
        const int nn = n0 + u * 16 + n16;
        #pragma unroll
        for (int s = 0; s < 2; ++s) {
            #pragma unroll
            for (int j = 0; j < 8; ++j) {
                const int q = s * 32 + quad * 8 + j;
                const float x = zb[(size_t)q * N_ + nn];
                zsq = fmaf(x, x, zsq);
                afrag[u][s][j] = f2bf(-2.f * x);   // exact pow2 scale
            }
        }
    }

    // ---- issue ALL 8 B-tiles (bf16, 2 x 16B/lane/tile) + e2 (L2-hot) ----
    const short* bb = embB + (w * 128 + n16) * Q_ + quad * 8;
    bf16x8 Bv[8][2];
    float  e2v[8];
    #pragma unroll
    for (int t = 0; t < 8; ++t) {
        Bv[t][0] = *(const bf16x8*)(bb + t * 16 * Q_);
        Bv[t][1] = *(const bf16x8*)(bb + t * 16 * Q_ + 32);
        e2v[t]   = e2g[w * 128 + t * 16 + n16];
    }

    // ---- 8 tiles back-to-back from registers ----
    f32x4 best[4];
    #pragma unroll
    for (int u = 0; u < 4; ++u) best[u] = (f32x4){1e30f, 1e30f, 1e30f, 1e30f};

    #pragma unroll
    for (int t = 0; t < 8; ++t) {
        const f32x4 ce2 = {e2v[t], e2v[t], e2v[t], e2v[t]};
        #pragma unroll
        for (int u = 0; u < 4; ++u) {        // 4 independent MFMA chains
            f32x4 a = __builtin_amdgcn_mfma_f32_16x16x32_bf16(afrag[u][0], Bv[t][0], ce2, 0, 0, 0);
            a       = __builtin_amdgcn_mfma_f32_16x16x32_bf16(afrag[u][1], Bv[t][1], a,   0, 0, 0);
            #pragma unroll
            for (int r = 0; r < 4; ++r) best[u][r] = fminf(best[u][r], a[r]);
        }
    }

    // ---- min over this wave's 16 cw columns; stash per-item mins ----
    #pragma unroll
    for (int m = 1; m < 16; m <<= 1) {
        #pragma unroll
        for (int u = 0; u < 4; ++u) {
            #pragma unroll
            for (int r = 0; r < 4; ++r)
                best[u][r] = fminf(best[u][r], __shfl_xor(best[u][r], m, 64));
        }
    }
    if (n16 == 0) {                          // lanes 0,16,32,48
        #pragma unroll
        for (int u = 0; u < 4; ++u) {
            #pragma unroll
            for (int r = 0; r < 4; ++r)      // item = u*16 + quad*4 + r
                smem[w * 64 + u * 16 + quad * 4 + r] = best[u][r];
        }
    }
    __syncthreads();

    // ---- finalize (wave 0; zsq over wave 0 covers all 64 items) ----
    if (w == 0) {
        const float mn = fminf(fminf(smem[lane], smem[64 + lane]),
                               fminf(smem[128 + lane], smem[192 + lane]));
        float val = 1.25f * (mn + zsq);
        #pragma unroll
        for (int off = 32; off > 0; off >>= 1) val += __shfl_down(val, off, 64);
        if (lane == 0) vqPart[blockIdx.x] = val;
    }
}

// ---------------------------------------------------------------------------
// reduce: deterministic sum of 256 CE partials + 1024 VQ partials -> out.
// ---------------------------------------------------------------------------
__global__ __launch_bounds__(256) void reduce_kernel(const float* __restrict__ cePart,
                                                     const float* __restrict__ vqPart,
                                                     float* __restrict__ out)
{
    __shared__ float sm[4];
    const int tid = threadIdx.x;
    float s = cePart[tid];
    #pragma unroll
    for (int i = 0; i < 4; ++i) s += vqPart[tid + i * 256];
    #pragma unroll
    for (int off = 32; off > 0; off >>= 1) s += __shfl_down(s, off, 64);
    if ((tid & 63) == 0) sm[tid >> 6] = s;
    __syncthreads();
    if (tid == 0) out[0] = (sm[0] + sm[1]) + (sm[2] + sm[3]);
}

extern "C" void kernel_launch(void* const* d_in, const int* in_sizes, int n_in,
                              void* d_out, int out_size, void* d_ws, size_t ws_size,
                              hipStream_t stream) {
    const float* ze  = (const float*)d_in[0];
    const float* emb = (const float*)d_in[1];
    const float* qp  = (const float*)d_in[2];
    const int*   tgt = (const int*)d_in[3];
    float* out = (float*)d_out;

    short* embB   = (short*)d_ws;                                    // 64 KB
    float* e2g    = (float*)((char*)d_ws + 65536);                   // +2 KB
    float* cePart = (float*)((char*)d_ws + 65536 + 2048);            // +1 KB
    float* vqPart = (float*)((char*)d_ws + 65536 + 2048 + 1024);     // +4 KB

    ce_kernel<<<256, 512, 0, stream>>>(qp, tgt, cePart);
    prep_kernel<<<2, 256, 0, stream>>>(emb, embB, e2g);
    vq_kernel<<<1024, 256, 0, stream>>>(ze, embB, e2g, vqPart);
    reduce_kernel<<<1, 256, 0, stream>>>(cePart, vqPart, out);
}